// Round 7
// baseline (636.217 us; speedup 1.0000x reference)
//
#include <hip/hip_runtime.h>
#include <hip/hip_bf16.h>
#include <math.h>

// DiT attention block — f16-split (hi+lo) MFMA pipeline, swapped-QK^T flash,
// 2-phase double-buffered LDS staging (T3 minimum recipe) in GEMM and flash.
// B=4 L=2048 D=1024 H=16 HD=64.

#define NB 4
#define NL 2048
#define ND 1024
#define NH 16
#define NHD 64
#define GM (NB * NL)  // 8192

typedef _Float16 f16;
typedef _Float16 half4v __attribute__((ext_vector_type(4)));
typedef _Float16 half8v __attribute__((ext_vector_type(8)));
typedef float f32x4 __attribute__((ext_vector_type(4)));

#define MFMA16(a, b, c) __builtin_amdgcn_mfma_f32_16x16x32_f16((a), (b), (c), 0, 0, 0)

__device__ __forceinline__ void gload16(const void* g, void* l) {
  __builtin_amdgcn_global_load_lds((const __attribute__((address_space(1))) void*)g,
                                   (__attribute__((address_space(3))) void*)l, 16, 0, 0);
}

// ---------------------------------------------------------------------------
// cos/sin table for RoPE: tbl[0..65535]=cos(l*invf(i)), tbl[65536..]=sin
// ---------------------------------------------------------------------------
__global__ __launch_bounds__(256) void sctable(float* __restrict__ tbl) {
  const int idx = blockIdx.x * 256 + threadIdx.x;  // 65536 = 2048*32
  const int l = idx >> 5, i = idx & 31;
  const float invf = exp2f(-(float)i * 0.41524101186092029f);  // (2/64)*log2(1e4)
  const float ang = (float)l * invf;
  tbl[idx] = cosf(ang);
  tbl[65536 + idx] = sinf(ang);
}

// ---------------------------------------------------------------------------
// hi/lo split of x (row-major passthrough)
// ---------------------------------------------------------------------------
__global__ __launch_bounds__(256) void presplit(const float* __restrict__ x,
                                                f16* __restrict__ xh,
                                                f16* __restrict__ xl) {
  const size_t i = ((size_t)blockIdx.x * 256 + threadIdx.x) * 4;
  const float4 v = *(const float4*)&x[i];
  half4v h, lo;
  h[0] = (f16)v.x; lo[0] = (f16)(v.x - (float)h[0]);
  h[1] = (f16)v.y; lo[1] = (f16)(v.y - (float)h[1]);
  h[2] = (f16)v.z; lo[2] = (f16)(v.z - (float)h[2]);
  h[3] = (f16)v.w; lo[3] = (f16)(v.w - (float)h[3]);
  *(half4v*)&xh[i] = h;
  *(half4v*)&xl[i] = lo;
}

// ---------------------------------------------------------------------------
// transpose + f16 hi/lo split: W[1024][N] fp32 -> Th/Tl [N][1024] f16
// ---------------------------------------------------------------------------
__global__ __launch_bounds__(256) void transplit(const float* __restrict__ Wsrc,
                                                 f16* __restrict__ Th,
                                                 f16* __restrict__ Tl, int N) {
  __shared__ float t[64][65];
  const int tid = threadIdx.x;
  const int n0 = blockIdx.x * 64, k0 = blockIdx.y * 64;
#pragma unroll
  for (int it = 0; it < 4; ++it) {
    const int e = it * 256 + tid;
    const int r = e >> 4, c4 = (e & 15) << 2;
    const float4 v = *(const float4*)&Wsrc[(size_t)(k0 + r) * N + n0 + c4];
    t[r][c4] = v.x; t[r][c4 + 1] = v.y; t[r][c4 + 2] = v.z; t[r][c4 + 3] = v.w;
  }
  __syncthreads();
#pragma unroll
  for (int it = 0; it < 4; ++it) {
    const int e = it * 256 + tid;
    const int rn = e >> 4, ck = (e & 15) << 2;
    half4v h, lo;
#pragma unroll
    for (int u = 0; u < 4; ++u) {
      const float v = t[ck + u][rn];
      const f16 hv = (f16)v;
      h[u] = hv;
      lo[u] = (f16)(v - (float)hv);
    }
    *(half4v*)&Th[(size_t)(n0 + rn) * 1024 + k0 + ck] = h;
    *(half4v*)&Tl[(size_t)(n0 + rn) * 1024 + k0 + ck] = lo;
  }
}

// ---------------------------------------------------------------------------
// Split-f16 GEMM: C = A[GM][1024] @ B^T[N][1024]^T + bias, via
// Ah*Bh + Ah*Bl + Al*Bh (16x16x32 f16 MFMA). 128x128 tile, BK=32, 4 waves.
// 2-phase double-buffered: STAGE(t+1) issued before compute(t); single
// barrier per K-step (implicit vmcnt/lgkm drain at __syncthreads).
// MODE=0: plain fp32 store. MODE=1: QKV epilogue (bias->rms->rope->split).
// ---------------------------------------------------------------------------
template <int N, int MODE>
__global__ __launch_bounds__(256) void gemm_split(
    const f16* __restrict__ Ah_g, const f16* __restrict__ Al_g,
    const f16* __restrict__ Bh_g, const f16* __restrict__ Bl_g,
    const float* __restrict__ bias, float* __restrict__ out32,
    f16* __restrict__ qh, f16* __restrict__ ql, f16* __restrict__ kh,
    f16* __restrict__ kl, f16* __restrict__ vth, const float* __restrict__ qw,
    const float* __restrict__ kw, const float* __restrict__ tbl) {
  __shared__ f16 Ah[2][4096], Al[2][4096], Bh[2][4096], Bl[2][4096];
  const int tid = threadIdx.x;
  const int ln = tid & 63, wv = tid >> 6;
  const int ln15 = ln & 15, q4 = ln >> 4;

  // XCD-aware bijective swizzle (nwg % 8 == 0)
  const int nwg = (N / 128) * (GM / 128);
  const int flat = blockIdx.y * gridDim.x + blockIdx.x;
  const int sw = (flat & 7) * (nwg >> 3) + (flat >> 3);
  const int bx = sw % (N / 128), by = sw / (N / 128);
  const int m0 = by * 128, n0 = bx * 128;
  const int wr = wv >> 1, wc = wv & 1;

  auto stage = [&](int buf, int k0) {
#pragma unroll
    for (int t = 0; t < 2; ++t) {
      const int f = wv * 2 + t;
      const size_t aoff = (size_t)(m0 + f * 16 + ln15) * 1024 + k0 + q4 * 8;
      const size_t boff = (size_t)(n0 + f * 16 + ln15) * 1024 + k0 + q4 * 8;
      gload16(Ah_g + aoff, &Ah[buf][f * 512]);
      gload16(Al_g + aoff, &Al[buf][f * 512]);
      gload16(Bh_g + boff, &Bh[buf][f * 512]);
      gload16(Bl_g + boff, &Bl[buf][f * 512]);
    }
  };

  f32x4 acc[4][4];
#pragma unroll
  for (int i = 0; i < 4; ++i)
#pragma unroll
    for (int j = 0; j < 4; ++j) acc[i][j] = (f32x4){0.f, 0.f, 0.f, 0.f};

  stage(0, 0);
  __syncthreads();

  for (int it = 0; it < 32; ++it) {
    const int cur = it & 1;
    if (it + 1 < 32) stage(cur ^ 1, (it + 1) * 32);

    half8v a_h[4], a_l[4];
#pragma unroll
    for (int i = 0; i < 4; ++i) {
      a_h[i] = *(half8v*)&Ah[cur][(wr * 4 + i) * 512 + ln * 8];
      a_l[i] = *(half8v*)&Al[cur][(wr * 4 + i) * 512 + ln * 8];
    }
#pragma unroll
    for (int j = 0; j < 4; ++j) {
      const half8v b_h = *(half8v*)&Bh[cur][(wc * 4 + j) * 512 + ln * 8];
      const half8v b_l = *(half8v*)&Bl[cur][(wc * 4 + j) * 512 + ln * 8];
#pragma unroll
      for (int i = 0; i < 4; ++i) {
        acc[i][j] = MFMA16(a_h[i], b_h, acc[i][j]);
        acc[i][j] = MFMA16(a_l[i], b_h, acc[i][j]);
        acc[i][j] = MFMA16(a_h[i], b_l, acc[i][j]);
      }
    }
    __syncthreads();  // drains stage(t+1) vmcnt + all waves done reading cur
  }

  // ---------------- epilogue ----------------
  const int nc = n0 + wc * 64;
  float bv[4];
#pragma unroll
  for (int j = 0; j < 4; ++j) bv[j] = bias[nc + j * 16 + ln15];

  if constexpr (MODE == 0) {
#pragma unroll
    for (int i = 0; i < 4; ++i) {
      const int m = m0 + wr * 64 + i * 16 + q4 * 4;
#pragma unroll
      for (int j = 0; j < 4; ++j)
#pragma unroll
        for (int r = 0; r < 4; ++r)
          out32[(size_t)(m + r) * N + nc + j * 16 + ln15] = acc[i][j][r] + bv[j];
    }
  } else {
    const int s = nc >> 10;          // 0=q 1=k 2=v
    const int h = (nc >> 6) & 15;    // head
    if (s == 2) {
      // V: plain f16, transposed [B,H,HD,L]
#pragma unroll
      for (int i = 0; i < 4; ++i) {
        const int m = m0 + wr * 64 + i * 16 + q4 * 4;
        const int b = m >> 11, l0 = m & (NL - 1);
#pragma unroll
        for (int j = 0; j < 4; ++j) {
          half4v pv;
#pragma unroll
          for (int r = 0; r < 4; ++r) pv[r] = (f16)(acc[i][j][r] + bv[j]);
          *(half4v*)&vth[(size_t)((b * NH + h) * NHD + j * 16 + ln15) * NL + l0] = pv;
        }
      }
    } else {
      const float* nw = (s == 0) ? qw : kw;
      f16* dh = (s == 0) ? qh : kh;
      f16* dl = (s == 0) ? ql : kl;
      // fold attention scale 1/8 and log2(e) into q
      const float qsc = (s == 0) ? 0.125f * 1.4426950408889634f : 1.0f;
      float wn[4];
#pragma unroll
      for (int j = 0; j < 4; ++j) wn[j] = nw[j * 16 + ln15];
#pragma unroll
      for (int i = 0; i < 4; ++i) {
        const int m = m0 + wr * 64 + i * 16 + q4 * 4;
        const int b = m >> 11, l0 = m & (NL - 1);
        float vv[4][4];
        float ss[4] = {0.f, 0.f, 0.f, 0.f};
#pragma unroll
        for (int j = 0; j < 4; ++j)
#pragma unroll
          for (int r = 0; r < 4; ++r) {
            vv[j][r] = acc[i][j][r] + bv[j];
            ss[r] += vv[j][r] * vv[j][r];
          }
#pragma unroll
        for (int r = 0; r < 4; ++r) {
          ss[r] += __shfl_xor(ss[r], 1);
          ss[r] += __shfl_xor(ss[r], 2);
          ss[r] += __shfl_xor(ss[r], 4);
          ss[r] += __shfl_xor(ss[r], 8);
          ss[r] = rsqrtf(ss[r] * (1.0f / 64.0f) + 1e-6f);
        }
#pragma unroll
        for (int j = 0; j < 4; ++j)
#pragma unroll
          for (int r = 0; r < 4; ++r) vv[j][r] *= ss[r] * wn[j];
        // rope: pair (hd, hd+32) = (j, j+2), angle index = jj*16+ln15
#pragma unroll
        for (int jj = 0; jj < 2; ++jj)
#pragma unroll
          for (int r = 0; r < 4; ++r) {
            const int l = l0 + r;
            const float c = tbl[l * 32 + jj * 16 + ln15];
            const float sn = tbl[65536 + l * 32 + jj * 16 + ln15];
            const float t1 = vv[jj][r], t2 = vv[jj + 2][r];
            vv[jj][r] = t1 * c - t2 * sn;
            vv[jj + 2][r] = t1 * sn + t2 * c;
          }
#pragma unroll
        for (int j = 0; j < 4; ++j)
#pragma unroll
          for (int r = 0; r < 4; ++r) {
            const float val = vv[j][r] * qsc;
            const f16 hv = (f16)val;
            const size_t di = (size_t)((b * NH + h) * NL + l0 + r) * NHD + j * 16 + ln15;
            dh[di] = hv;
            dl[di] = (f16)(val - (float)hv);
          }
      }
    }
  }
}

// ---------------------------------------------------------------------------
// Flash attention, swapped QK^T (S^T = K·Q^T), per-lane scalar softmax state,
// packed-P LDS round trip, defer-max. 2-phase double-buffered K/V staging:
// next tile's global_load_lds issued before current tile's compute; one
// barrier per KV tile. s_setprio(1) around MFMA clusters (T5).
// ---------------------------------------------------------------------------
__global__ __launch_bounds__(256) void flash_mfma(
    const f16* __restrict__ qh, const f16* __restrict__ ql,
    const f16* __restrict__ kh, const f16* __restrict__ kl,
    const f16* __restrict__ vth, f16* __restrict__ Oh, f16* __restrict__ Ol) {
  __shared__ f16 KH[2][4096], KL[2][4096], VT[2][4096];
  __shared__ f16 Pl[4][16][72];  // per-wave P slice, row stride 144 B
  const int tid = threadIdx.x;
  const int ln = tid & 63, wv = tid >> 6;
  const int ln15 = ln & 15, q4 = ln >> 4;

  // head-major XCD swizzle: each XCD gets 8 whole heads
  const int flat = blockIdx.x;  // 1024
  const int swz = (flat & 7) * 128 + (flat >> 3);
  const int head = swz >> 4;  // b*16+h
  const int qt = swz & 15;
  const int b = head >> 4, h = head & 15;
  const int q0 = qt * 128 + wv * 32;
  const size_t hbase = (size_t)head * NL * NHD;

  auto stage = [&](int buf, int kv0) {
#pragma unroll
    for (int t = 0; t < 6; ++t) {
      const int f = wv * 6 + t;
      if (f < 8) {
        gload16(kh + hbase + (size_t)(kv0 + (f >> 1) * 16 + ln15) * NHD + (f & 1) * 32 + q4 * 8,
                &KH[buf][f * 512]);
      } else if (f < 16) {
        const int g = f - 8;
        gload16(kl + hbase + (size_t)(kv0 + (g >> 1) * 16 + ln15) * NHD + (g & 1) * 32 + q4 * 8,
                &KL[buf][g * 512]);
      } else {
        const int g = f - 16;
        gload16(vth + (size_t)(head * NHD + (g >> 1) * 16 + ln15) * NL + kv0 + (g & 1) * 32 + q4 * 8,
                &VT[buf][g * 512]);
      }
    }
  };

  // Q fragments (serve as MFMA B-operand in swapped product)
  half8v qfh[2][2], qfl[2][2];
#pragma unroll
  for (int rf = 0; rf < 2; ++rf)
#pragma unroll
    for (int kb = 0; kb < 2; ++kb) {
      const size_t off = hbase + (size_t)(q0 + rf * 16 + ln15) * NHD + kb * 32 + q4 * 8;
      qfh[rf][kb] = *(const half8v*)&qh[off];
      qfl[rf][kb] = *(const half8v*)&ql[off];
    }

  f32x4 o_[4][2];  // O^T frag (df, rf): lane holds O[q=rf*16+ln15][d=df*16+q4*4+r]
  float m_[2], l_[2];
#pragma unroll
  for (int df = 0; df < 4; ++df)
#pragma unroll
    for (int rf = 0; rf < 2; ++rf) o_[df][rf] = (f32x4){0.f, 0.f, 0.f, 0.f};
  m_[0] = m_[1] = -INFINITY;
  l_[0] = l_[1] = 0.f;

  stage(0, 0);
  __syncthreads();

  for (int kt = 0; kt < NL / 64; ++kt) {
    const int cur = kt & 1;
    if (kt + 1 < NL / 64) stage(cur ^ 1, (kt + 1) * 64);

    // S^T = Kh·Qh + Kl·Qh + Kh·Ql  (C-frag: row=kv, col=q)
    f32x4 s_[2][4];
#pragma unroll
    for (int rf = 0; rf < 2; ++rf)
#pragma unroll
      for (int cb = 0; cb < 4; ++cb) s_[rf][cb] = (f32x4){0.f, 0.f, 0.f, 0.f};
    __builtin_amdgcn_s_setprio(1);
#pragma unroll
    for (int cb = 0; cb < 4; ++cb) {
      const half8v kh0 = *(half8v*)&KH[cur][(cb * 2 + 0) * 512 + ln * 8];
      const half8v kh1 = *(half8v*)&KH[cur][(cb * 2 + 1) * 512 + ln * 8];
      const half8v kl0 = *(half8v*)&KL[cur][(cb * 2 + 0) * 512 + ln * 8];
      const half8v kl1 = *(half8v*)&KL[cur][(cb * 2 + 1) * 512 + ln * 8];
#pragma unroll
      for (int rf = 0; rf < 2; ++rf) {
        f32x4 t = s_[rf][cb];
        t = MFMA16(kh0, qfh[rf][0], t);
        t = MFMA16(kh1, qfh[rf][1], t);
        t = MFMA16(kl0, qfh[rf][0], t);
        t = MFMA16(kl1, qfh[rf][1], t);
        t = MFMA16(kh0, qfl[rf][0], t);
        t = MFMA16(kh1, qfl[rf][1], t);
        s_[rf][cb] = t;
      }
    }
    __builtin_amdgcn_s_setprio(0);

    // per-rf: in-register online softmax + packed-P round trip + PV
#pragma unroll
    for (int rf = 0; rf < 2; ++rf) {
      float pmax = -INFINITY;
#pragma unroll
      for (int cb = 0; cb < 4; ++cb)
#pragma unroll
        for (int r = 0; r < 4; ++r) pmax = fmaxf(pmax, s_[rf][cb][r]);
      pmax = fmaxf(pmax, __shfl_xor(pmax, 16));
      pmax = fmaxf(pmax, __shfl_xor(pmax, 32));
      if (!__all(pmax - m_[rf] <= 8.0f)) {  // defer-max: skip rescale usually
        const float mn = fmaxf(m_[rf], pmax);
        const float al = exp2f(m_[rf] - mn);
        m_[rf] = mn;
        l_[rf] *= al;
#pragma unroll
        for (int df = 0; df < 4; ++df) o_[df][rf] *= al;
      }
      float rs = 0.f;
#pragma unroll
      for (int cb = 0; cb < 4; ++cb) {
        half4v pk;
#pragma unroll
        for (int r = 0; r < 4; ++r) {
          const float p = exp2f(s_[rf][cb][r] - m_[rf]);
          rs += p;
          pk[r] = (f16)p;
        }
        *(half4v*)&Pl[wv][ln15][cb * 16 + q4 * 4] = pk;  // P[q=ln15][kv]
      }
      rs += __shfl_xor(rs, 16);
      rs += __shfl_xor(rs, 32);
      l_[rf] += rs;

      // O^T += V^T · P^T
      __builtin_amdgcn_s_setprio(1);
#pragma unroll
      for (int ks = 0; ks < 2; ++ks) {
        const half8v pb = *(half8v*)&Pl[wv][ln15][ks * 32 + q4 * 8];
#pragma unroll
        for (int df = 0; df < 4; ++df) {
          const half8v vb = *(half8v*)&VT[cur][(df * 2 + ks) * 512 + ln * 8];
          o_[df][rf] = MFMA16(vb, pb, o_[df][rf]);
        }
      }
      __builtin_amdgcn_s_setprio(0);
    }
    __syncthreads();  // drains stage(kt+1) vmcnt + all waves done with cur
  }

  // epilogue: normalize, split, write O [B*L][D]
#pragma unroll
  for (int rf = 0; rf < 2; ++rf) {
    const float invl = 1.0f / l_[rf];
    const int q = q0 + rf * 16 + ln15;
    const size_t rowb = (size_t)(b * NL + q) * ND + h * 64;
#pragma unroll
    for (int df = 0; df < 4; ++df) {
      half4v oh_, ol_;
#pragma unroll
      for (int r = 0; r < 4; ++r) {
        const float val = o_[df][rf][r] * invl;
        const f16 hv = (f16)val;
        oh_[r] = hv;
        ol_[r] = (f16)(val - (float)hv);
      }
      *(half4v*)&Oh[rowb + df * 16 + q4 * 4] = oh_;
      *(half4v*)&Ol[rowb + df * 16 + q4 * 4] = ol_;
    }
  }
}

// ---------------------------------------------------------------------------
extern "C" void kernel_launch(void* const* d_in, const int* in_sizes, int n_in,
                              void* d_out, int out_size, void* d_ws,
                              size_t ws_size, hipStream_t stream) {
  const float* x = (const float*)d_in[0];
  const float* Wqkv = (const float*)d_in[1];
  const float* bqkv = (const float*)d_in[2];
  const float* qn_w = (const float*)d_in[3];
  const float* kn_w = (const float*)d_in[4];
  const float* Wout = (const float*)d_in[5];
  const float* bout = (const float*)d_in[6];
  float* out = (float*)d_out;

  char* wsb = (char*)d_ws;
  // [0,80): qh|ql|kh|kl|vth (16 MiB each). [80,80.5): rope table.
  // [81,93) WqT h/l, [93,125) xh/xl  (dead after gemm1)
  // [81,113) Oh/Ol (flash output), [113,117) WoT h/l (written after gemm1).
  f16* qh = (f16*)(wsb);
  f16* ql = (f16*)(wsb + (16u << 20));
  f16* kh = (f16*)(wsb + (32u << 20));
  f16* kl = (f16*)(wsb + (48u << 20));
  f16* vth = (f16*)(wsb + (64u << 20));
  float* tbl = (float*)(wsb + (80u << 20));
  f16* WqTh = (f16*)(wsb + (81u << 20));
  f16* WqTl = (f16*)(wsb + (87u << 20));
  f16* xh = (f16*)(wsb + (93u << 20));
  f16* xl = (f16*)(wsb + (109u << 20));
  f16* Oh = (f16*)(wsb + (81u << 20));
  f16* Ol = (f16*)(wsb + (97u << 20));
  f16* WoTh = (f16*)(wsb + (113u << 20));
  f16* WoTl = (f16*)(wsb + (115u << 20));

  sctable<<<256, 256, 0, stream>>>(tbl);
  transplit<<<dim3(48, 16), 256, 0, stream>>>(Wqkv, WqTh, WqTl, 3 * ND);
  presplit<<<8192, 256, 0, stream>>>(x, xh, xl);

  gemm_split<3 * ND, 1><<<dim3(24, 64), 256, 0, stream>>>(
      xh, xl, WqTh, WqTl, bqkv, nullptr, qh, ql, kh, kl, vth, qn_w, kn_w, tbl);

  transplit<<<dim3(16, 16), 256, 0, stream>>>(Wout, WoTh, WoTl, ND);

  flash_mfma<<<1024, 256, 0, stream>>>(qh, ql, kh, kl, vth, Oh, Ol);

  gemm_split<ND, 0><<<dim3(8, 64), 256, 0, stream>>>(
      Oh, Ol, WoTh, WoTl, bout, out, nullptr, nullptr, nullptr, nullptr,
      nullptr, nullptr, nullptr, nullptr);
}

// Round 8
// 566.057 us; speedup vs baseline: 1.1239x; 1.1239x over previous
//
#include <hip/hip_runtime.h>
#include <hip/hip_bf16.h>
#include <math.h>

// DiT attention block — f16-split (hi+lo) MFMA pipeline.
// GEMMs: single-buffered 32KB LDS (R3 structure; dbuf regressed — m132 trap).
// Flash: swapped-QK^T, 2-phase double-buffered staging + setprio (R7, helped).
// B=4 L=2048 D=1024 H=16 HD=64.

#define NB 4
#define NL 2048
#define ND 1024
#define NH 16
#define NHD 64
#define GM (NB * NL)  // 8192

typedef _Float16 f16;
typedef _Float16 half4v __attribute__((ext_vector_type(4)));
typedef _Float16 half8v __attribute__((ext_vector_type(8)));
typedef float f32x4 __attribute__((ext_vector_type(4)));

#define MFMA16(a, b, c) __builtin_amdgcn_mfma_f32_16x16x32_f16((a), (b), (c), 0, 0, 0)

__device__ __forceinline__ void gload16(const void* g, void* l) {
  __builtin_amdgcn_global_load_lds((const __attribute__((address_space(1))) void*)g,
                                   (__attribute__((address_space(3))) void*)l, 16, 0, 0);
}

// ---------------------------------------------------------------------------
// cos/sin table for RoPE: tbl[0..65535]=cos(l*invf(i)), tbl[65536..]=sin
// ---------------------------------------------------------------------------
__global__ __launch_bounds__(256) void sctable(float* __restrict__ tbl) {
  const int idx = blockIdx.x * 256 + threadIdx.x;  // 65536 = 2048*32
  const int l = idx >> 5, i = idx & 31;
  const float invf = exp2f(-(float)i * 0.41524101186092029f);  // (2/64)*log2(1e4)
  const float ang = (float)l * invf;
  tbl[idx] = cosf(ang);
  tbl[65536 + idx] = sinf(ang);
}

// ---------------------------------------------------------------------------
// hi/lo split of x (row-major passthrough)
// ---------------------------------------------------------------------------
__global__ __launch_bounds__(256) void presplit(const float* __restrict__ x,
                                                f16* __restrict__ xh,
                                                f16* __restrict__ xl) {
  const size_t i = ((size_t)blockIdx.x * 256 + threadIdx.x) * 4;
  const float4 v = *(const float4*)&x[i];
  half4v h, lo;
  h[0] = (f16)v.x; lo[0] = (f16)(v.x - (float)h[0]);
  h[1] = (f16)v.y; lo[1] = (f16)(v.y - (float)h[1]);
  h[2] = (f16)v.z; lo[2] = (f16)(v.z - (float)h[2]);
  h[3] = (f16)v.w; lo[3] = (f16)(v.w - (float)h[3]);
  *(half4v*)&xh[i] = h;
  *(half4v*)&xl[i] = lo;
}

// ---------------------------------------------------------------------------
// transpose + f16 hi/lo split: W[1024][N] fp32 -> Th/Tl [N][1024] f16
// ---------------------------------------------------------------------------
__global__ __launch_bounds__(256) void transplit(const float* __restrict__ Wsrc,
                                                 f16* __restrict__ Th,
                                                 f16* __restrict__ Tl, int N) {
  __shared__ float t[64][65];
  const int tid = threadIdx.x;
  const int n0 = blockIdx.x * 64, k0 = blockIdx.y * 64;
#pragma unroll
  for (int it = 0; it < 4; ++it) {
    const int e = it * 256 + tid;
    const int r = e >> 4, c4 = (e & 15) << 2;
    const float4 v = *(const float4*)&Wsrc[(size_t)(k0 + r) * N + n0 + c4];
    t[r][c4] = v.x; t[r][c4 + 1] = v.y; t[r][c4 + 2] = v.z; t[r][c4 + 3] = v.w;
  }
  __syncthreads();
#pragma unroll
  for (int it = 0; it < 4; ++it) {
    const int e = it * 256 + tid;
    const int rn = e >> 4, ck = (e & 15) << 2;
    half4v h, lo;
#pragma unroll
    for (int u = 0; u < 4; ++u) {
      const float v = t[ck + u][rn];
      const f16 hv = (f16)v;
      h[u] = hv;
      lo[u] = (f16)(v - (float)hv);
    }
    *(half4v*)&Th[(size_t)(n0 + rn) * 1024 + k0 + ck] = h;
    *(half4v*)&Tl[(size_t)(n0 + rn) * 1024 + k0 + ck] = lo;
  }
}

// ---------------------------------------------------------------------------
// Split-f16 GEMM: C = A[GM][1024] @ B^T[N][1024]^T + bias, via
// Ah*Bh + Ah*Bl + Al*Bh (16x16x32 f16 MFMA). 128x128 tile, BK=32, 4 waves.
// SINGLE-buffered 32KB LDS: 4-5 blocks/CU; cross-block wave overlap (m114)
// hides staging latency. Dbuf (64KB) measured -36% here (R7; m132 trap).
// MODE=0: plain fp32 store. MODE=1: QKV epilogue (bias->rms->rope->split).
// ---------------------------------------------------------------------------
template <int N, int MODE>
__global__ __launch_bounds__(256) void gemm_split(
    const f16* __restrict__ Ah_g, const f16* __restrict__ Al_g,
    const f16* __restrict__ Bh_g, const f16* __restrict__ Bl_g,
    const float* __restrict__ bias, float* __restrict__ out32,
    f16* __restrict__ qh, f16* __restrict__ ql, f16* __restrict__ kh,
    f16* __restrict__ kl, f16* __restrict__ vth, const float* __restrict__ qw,
    const float* __restrict__ kw, const float* __restrict__ tbl) {
  __shared__ f16 Ah[4096], Al[4096], Bh[4096], Bl[4096];
  const int tid = threadIdx.x;
  const int ln = tid & 63, wv = tid >> 6;
  const int ln15 = ln & 15, q4 = ln >> 4;

  // XCD-aware bijective swizzle (nwg % 8 == 0)
  const int nwg = (N / 128) * (GM / 128);
  const int flat = blockIdx.y * gridDim.x + blockIdx.x;
  const int sw = (flat & 7) * (nwg >> 3) + (flat >> 3);
  const int bx = sw % (N / 128), by = sw / (N / 128);
  const int m0 = by * 128, n0 = bx * 128;
  const int wr = wv >> 1, wc = wv & 1;

  f32x4 acc[4][4];
#pragma unroll
  for (int i = 0; i < 4; ++i)
#pragma unroll
    for (int j = 0; j < 4; ++j) acc[i][j] = (f32x4){0.f, 0.f, 0.f, 0.f};

  for (int k0 = 0; k0 < 1024; k0 += 32) {
#pragma unroll
    for (int t = 0; t < 2; ++t) {
      const int f = wv * 2 + t;
      const size_t aoff = (size_t)(m0 + f * 16 + ln15) * 1024 + k0 + q4 * 8;
      const size_t boff = (size_t)(n0 + f * 16 + ln15) * 1024 + k0 + q4 * 8;
      gload16(Ah_g + aoff, &Ah[f * 512]);
      gload16(Al_g + aoff, &Al[f * 512]);
      gload16(Bh_g + boff, &Bh[f * 512]);
      gload16(Bl_g + boff, &Bl[f * 512]);
    }
    __syncthreads();

    half8v a_h[4], a_l[4];
#pragma unroll
    for (int i = 0; i < 4; ++i) {
      a_h[i] = *(half8v*)&Ah[(wr * 4 + i) * 512 + ln * 8];
      a_l[i] = *(half8v*)&Al[(wr * 4 + i) * 512 + ln * 8];
    }
#pragma unroll
    for (int j = 0; j < 4; ++j) {
      const half8v b_h = *(half8v*)&Bh[(wc * 4 + j) * 512 + ln * 8];
      const half8v b_l = *(half8v*)&Bl[(wc * 4 + j) * 512 + ln * 8];
#pragma unroll
      for (int i = 0; i < 4; ++i) {
        acc[i][j] = MFMA16(a_h[i], b_h, acc[i][j]);
        acc[i][j] = MFMA16(a_l[i], b_h, acc[i][j]);
        acc[i][j] = MFMA16(a_h[i], b_l, acc[i][j]);
      }
    }
    __syncthreads();
  }

  // ---------------- epilogue ----------------
  const int nc = n0 + wc * 64;
  float bv[4];
#pragma unroll
  for (int j = 0; j < 4; ++j) bv[j] = bias[nc + j * 16 + ln15];

  if constexpr (MODE == 0) {
#pragma unroll
    for (int i = 0; i < 4; ++i) {
      const int m = m0 + wr * 64 + i * 16 + q4 * 4;
#pragma unroll
      for (int j = 0; j < 4; ++j)
#pragma unroll
        for (int r = 0; r < 4; ++r)
          out32[(size_t)(m + r) * N + nc + j * 16 + ln15] = acc[i][j][r] + bv[j];
    }
  } else {
    const int s = nc >> 10;          // 0=q 1=k 2=v
    const int h = (nc >> 6) & 15;    // head
    if (s == 2) {
      // V: plain f16, transposed [B,H,HD,L]
#pragma unroll
      for (int i = 0; i < 4; ++i) {
        const int m = m0 + wr * 64 + i * 16 + q4 * 4;
        const int b = m >> 11, l0 = m & (NL - 1);
#pragma unroll
        for (int j = 0; j < 4; ++j) {
          half4v pv;
#pragma unroll
          for (int r = 0; r < 4; ++r) pv[r] = (f16)(acc[i][j][r] + bv[j]);
          *(half4v*)&vth[(size_t)((b * NH + h) * NHD + j * 16 + ln15) * NL + l0] = pv;
        }
      }
    } else {
      const float* nw = (s == 0) ? qw : kw;
      f16* dh = (s == 0) ? qh : kh;
      f16* dl = (s == 0) ? ql : kl;
      // fold attention scale 1/8 and log2(e) into q
      const float qsc = (s == 0) ? 0.125f * 1.4426950408889634f : 1.0f;
      float wn[4];
#pragma unroll
      for (int j = 0; j < 4; ++j) wn[j] = nw[j * 16 + ln15];
#pragma unroll
      for (int i = 0; i < 4; ++i) {
        const int m = m0 + wr * 64 + i * 16 + q4 * 4;
        const int b = m >> 11, l0 = m & (NL - 1);
        float vv[4][4];
        float ss[4] = {0.f, 0.f, 0.f, 0.f};
#pragma unroll
        for (int j = 0; j < 4; ++j)
#pragma unroll
          for (int r = 0; r < 4; ++r) {
            vv[j][r] = acc[i][j][r] + bv[j];
            ss[r] += vv[j][r] * vv[j][r];
          }
#pragma unroll
        for (int r = 0; r < 4; ++r) {
          ss[r] += __shfl_xor(ss[r], 1);
          ss[r] += __shfl_xor(ss[r], 2);
          ss[r] += __shfl_xor(ss[r], 4);
          ss[r] += __shfl_xor(ss[r], 8);
          ss[r] = rsqrtf(ss[r] * (1.0f / 64.0f) + 1e-6f);
        }
#pragma unroll
        for (int j = 0; j < 4; ++j)
#pragma unroll
          for (int r = 0; r < 4; ++r) vv[j][r] *= ss[r] * wn[j];
        // rope: pair (hd, hd+32) = (j, j+2), angle index = jj*16+ln15
#pragma unroll
        for (int jj = 0; jj < 2; ++jj)
#pragma unroll
          for (int r = 0; r < 4; ++r) {
            const int l = l0 + r;
            const float c = tbl[l * 32 + jj * 16 + ln15];
            const float sn = tbl[65536 + l * 32 + jj * 16 + ln15];
            const float t1 = vv[jj][r], t2 = vv[jj + 2][r];
            vv[jj][r] = t1 * c - t2 * sn;
            vv[jj + 2][r] = t1 * sn + t2 * c;
          }
#pragma unroll
        for (int j = 0; j < 4; ++j)
#pragma unroll
          for (int r = 0; r < 4; ++r) {
            const float val = vv[j][r] * qsc;
            const f16 hv = (f16)val;
            const size_t di = (size_t)((b * NH + h) * NL + l0 + r) * NHD + j * 16 + ln15;
            dh[di] = hv;
            dl[di] = (f16)(val - (float)hv);
          }
      }
    }
  }
}

// ---------------------------------------------------------------------------
// Flash attention, swapped QK^T (S^T = K·Q^T), per-lane scalar softmax state,
// packed-P LDS round trip, defer-max. 2-phase double-buffered K/V staging:
// next tile's global_load_lds issued before current tile's compute; one
// barrier per KV tile. s_setprio(1) around MFMA clusters (T5).
// (Kept from R7 — flash improved there; only the GEMMs regressed.)
// ---------------------------------------------------------------------------
__global__ __launch_bounds__(256) void flash_mfma(
    const f16* __restrict__ qh, const f16* __restrict__ ql,
    const f16* __restrict__ kh, const f16* __restrict__ kl,
    const f16* __restrict__ vth, f16* __restrict__ Oh, f16* __restrict__ Ol) {
  __shared__ f16 KH[2][4096], KL[2][4096], VT[2][4096];
  __shared__ f16 Pl[4][16][72];  // per-wave P slice, row stride 144 B
  const int tid = threadIdx.x;
  const int ln = tid & 63, wv = tid >> 6;
  const int ln15 = ln & 15, q4 = ln >> 4;

  // head-major XCD swizzle: each XCD gets 8 whole heads
  const int flat = blockIdx.x;  // 1024
  const int swz = (flat & 7) * 128 + (flat >> 3);
  const int head = swz >> 4;  // b*16+h
  const int qt = swz & 15;
  const int b = head >> 4, h = head & 15;
  const int q0 = qt * 128 + wv * 32;
  const size_t hbase = (size_t)head * NL * NHD;

  auto stage = [&](int buf, int kv0) {
#pragma unroll
    for (int t = 0; t < 6; ++t) {
      const int f = wv * 6 + t;
      if (f < 8) {
        gload16(kh + hbase + (size_t)(kv0 + (f >> 1) * 16 + ln15) * NHD + (f & 1) * 32 + q4 * 8,
                &KH[buf][f * 512]);
      } else if (f < 16) {
        const int g = f - 8;
        gload16(kl + hbase + (size_t)(kv0 + (g >> 1) * 16 + ln15) * NHD + (g & 1) * 32 + q4 * 8,
                &KL[buf][g * 512]);
      } else {
        const int g = f - 16;
        gload16(vth + (size_t)(head * NHD + (g >> 1) * 16 + ln15) * NL + kv0 + (g & 1) * 32 + q4 * 8,
                &VT[buf][g * 512]);
      }
    }
  };

  // Q fragments (serve as MFMA B-operand in swapped product)
  half8v qfh[2][2], qfl[2][2];
#pragma unroll
  for (int rf = 0; rf < 2; ++rf)
#pragma unroll
    for (int kb = 0; kb < 2; ++kb) {
      const size_t off = hbase + (size_t)(q0 + rf * 16 + ln15) * NHD + kb * 32 + q4 * 8;
      qfh[rf][kb] = *(const half8v*)&qh[off];
      qfl[rf][kb] = *(const half8v*)&ql[off];
    }

  f32x4 o_[4][2];  // O^T frag (df, rf): lane holds O[q=rf*16+ln15][d=df*16+q4*4+r]
  float m_[2], l_[2];
#pragma unroll
  for (int df = 0; df < 4; ++df)
#pragma unroll
    for (int rf = 0; rf < 2; ++rf) o_[df][rf] = (f32x4){0.f, 0.f, 0.f, 0.f};
  m_[0] = m_[1] = -INFINITY;
  l_[0] = l_[1] = 0.f;

  stage(0, 0);
  __syncthreads();

  for (int kt = 0; kt < NL / 64; ++kt) {
    const int cur = kt & 1;
    if (kt + 1 < NL / 64) stage(cur ^ 1, (kt + 1) * 64);

    // S^T = Kh·Qh + Kl·Qh + Kh·Ql  (C-frag: row=kv, col=q)
    f32x4 s_[2][4];
#pragma unroll
    for (int rf = 0; rf < 2; ++rf)
#pragma unroll
      for (int cb = 0; cb < 4; ++cb) s_[rf][cb] = (f32x4){0.f, 0.f, 0.f, 0.f};
    __builtin_amdgcn_s_setprio(1);
#pragma unroll
    for (int cb = 0; cb < 4; ++cb) {
      const half8v kh0 = *(half8v*)&KH[cur][(cb * 2 + 0) * 512 + ln * 8];
      const half8v kh1 = *(half8v*)&KH[cur][(cb * 2 + 1) * 512 + ln * 8];
      const half8v kl0 = *(half8v*)&KL[cur][(cb * 2 + 0) * 512 + ln * 8];
      const half8v kl1 = *(half8v*)&KL[cur][(cb * 2 + 1) * 512 + ln * 8];
#pragma unroll
      for (int rf = 0; rf < 2; ++rf) {
        f32x4 t = s_[rf][cb];
        t = MFMA16(kh0, qfh[rf][0], t);
        t = MFMA16(kh1, qfh[rf][1], t);
        t = MFMA16(kl0, qfh[rf][0], t);
        t = MFMA16(kl1, qfh[rf][1], t);
        t = MFMA16(kh0, qfl[rf][0], t);
        t = MFMA16(kh1, qfl[rf][1], t);
        s_[rf][cb] = t;
      }
    }
    __builtin_amdgcn_s_setprio(0);

    // per-rf: in-register online softmax + packed-P round trip + PV
#pragma unroll
    for (int rf = 0; rf < 2; ++rf) {
      float pmax = -INFINITY;
#pragma unroll
      for (int cb = 0; cb < 4; ++cb)
#pragma unroll
        for (int r = 0; r < 4; ++r) pmax = fmaxf(pmax, s_[rf][cb][r]);
      pmax = fmaxf(pmax, __shfl_xor(pmax, 16));
      pmax = fmaxf(pmax, __shfl_xor(pmax, 32));
      if (!__all(pmax - m_[rf] <= 8.0f)) {  // defer-max: skip rescale usually
        const float mn = fmaxf(m_[rf], pmax);
        const float al = exp2f(m_[rf] - mn);
        m_[rf] = mn;
        l_[rf] *= al;
#pragma unroll
        for (int df = 0; df < 4; ++df) o_[df][rf] *= al;
      }
      float rs = 0.f;
#pragma unroll
      for (int cb = 0; cb < 4; ++cb) {
        half4v pk;
#pragma unroll
        for (int r = 0; r < 4; ++r) {
          const float p = exp2f(s_[rf][cb][r] - m_[rf]);
          rs += p;
          pk[r] = (f16)p;
        }
        *(half4v*)&Pl[wv][ln15][cb * 16 + q4 * 4] = pk;  // P[q=ln15][kv]
      }
      rs += __shfl_xor(rs, 16);
      rs += __shfl_xor(rs, 32);
      l_[rf] += rs;

      // O^T += V^T · P^T
      __builtin_amdgcn_s_setprio(1);
#pragma unroll
      for (int ks = 0; ks < 2; ++ks) {
        const half8v pb = *(half8v*)&Pl[wv][ln15][ks * 32 + q4 * 8];
#pragma unroll
        for (int df = 0; df < 4; ++df) {
          const half8v vb = *(half8v*)&VT[cur][(df * 2 + ks) * 512 + ln * 8];
          o_[df][rf] = MFMA16(vb, pb, o_[df][rf]);
        }
      }
      __builtin_amdgcn_s_setprio(0);
    }
    __syncthreads();  // drains stage(kt+1) vmcnt + all waves done with cur
  }

  // epilogue: normalize, split, write O [B*L][D]
#pragma unroll
  for (int rf = 0; rf < 2; ++rf) {
    const float invl = 1.0f / l_[rf];
    const int q = q0 + rf * 16 + ln15;
    const size_t rowb = (size_t)(b * NL + q) * ND + h * 64;
#pragma unroll
    for (int df = 0; df < 4; ++df) {
      half4v oh_, ol_;
#pragma unroll
      for (int r = 0; r < 4; ++r) {
        const float val = o_[df][rf][r] * invl;
        const f16 hv = (f16)val;
        oh_[r] = hv;
        ol_[r] = (f16)(val - (float)hv);
      }
      *(half4v*)&Oh[rowb + df * 16 + q4 * 4] = oh_;
      *(half4v*)&Ol[rowb + df * 16 + q4 * 4] = ol_;
    }
  }
}

// ---------------------------------------------------------------------------
extern "C" void kernel_launch(void* const* d_in, const int* in_sizes, int n_in,
                              void* d_out, int out_size, void* d_ws,
                              size_t ws_size, hipStream_t stream) {
  const float* x = (const float*)d_in[0];
  const float* Wqkv = (const float*)d_in[1];
  const float* bqkv = (const float*)d_in[2];
  const float* qn_w = (const float*)d_in[3];
  const float* kn_w = (const float*)d_in[4];
  const float* Wout = (const float*)d_in[5];
  const float* bout = (const float*)d_in[6];
  float* out = (float*)d_out;

  char* wsb = (char*)d_ws;
  // [0,80): qh|ql|kh|kl|vth (16 MiB each). [80,80.5): rope table.
  // [81,93) WqT h/l, [93,125) xh/xl  (dead after gemm1)
  // [81,113) Oh/Ol (flash output), [113,117) WoT h/l (written after gemm1).
  f16* qh = (f16*)(wsb);
  f16* ql = (f16*)(wsb + (16u << 20));
  f16* kh = (f16*)(wsb + (32u << 20));
  f16* kl = (f16*)(wsb + (48u << 20));
  f16* vth = (f16*)(wsb + (64u << 20));
  float* tbl = (float*)(wsb + (80u << 20));
  f16* WqTh = (f16*)(wsb + (81u << 20));
  f16* WqTl = (f16*)(wsb + (87u << 20));
  f16* xh = (f16*)(wsb + (93u << 20));
  f16* xl = (f16*)(wsb + (109u << 20));
  f16* Oh = (f16*)(wsb + (81u << 20));
  f16* Ol = (f16*)(wsb + (97u << 20));
  f16* WoTh = (f16*)(wsb + (113u << 20));
  f16* WoTl = (f16*)(wsb + (115u << 20));

  sctable<<<256, 256, 0, stream>>>(tbl);
  transplit<<<dim3(48, 16), 256, 0, stream>>>(Wqkv, WqTh, WqTl, 3 * ND);
  presplit<<<8192, 256, 0, stream>>>(x, xh, xl);

  gemm_split<3 * ND, 1><<<dim3(24, 64), 256, 0, stream>>>(
      xh, xl, WqTh, WqTl, bqkv, nullptr, qh, ql, kh, kl, vth, qn_w, kn_w, tbl);

  transplit<<<dim3(16, 16), 256, 0, stream>>>(Wout, WoTh, WoTl, ND);

  flash_mfma<<<1024, 256, 0, stream>>>(qh, ql, kh, kl, vth, Oh, Ol);

  gemm_split<ND, 0><<<dim3(8, 64), 256, 0, stream>>>(
      Oh, Ol, WoTh, WoTl, bout, out, nullptr, nullptr, nullptr, nullptr,
      nullptr, nullptr, nullptr, nullptr);
}